// Round 1
// baseline (194.528 us; speedup 1.0000x reference)
//
#include <hip/hip_runtime.h>
#include <stdint.h>

// Problem constants (B,C,H,W = 8,256,48,48)
#define NB  8
#define NC  256
#define NCR 32
#define NSP 2304  // N = H*W
#define LOG2E 1.44269504088896340736f

typedef __attribute__((ext_vector_type(8))) short short8;   // 8 x bf16 (4 VGPRs)
typedef __attribute__((ext_vector_type(4))) float f32x4;    // MFMA C/D frag
typedef __attribute__((ext_vector_type(4))) unsigned short us4;
typedef __attribute__((ext_vector_type(2))) unsigned int u32x2;

__device__ __forceinline__ unsigned short f2bf(float f) {
  union { float f; unsigned u; } a; a.f = f;
  unsigned r = (a.u + 0x7FFFu + ((a.u >> 16) & 1u)) >> 16;  // RNE
  return (unsigned short)r;
}

__device__ __forceinline__ float fexp2(float x) {
#if __has_builtin(__builtin_amdgcn_exp2f)
  return __builtin_amdgcn_exp2f(x);
#else
  return __exp2f(x);
#endif
}

// pack 4 fp32 -> 4 bf16 (RNE) as two dwords
__device__ __forceinline__ u32x2 pack4bf(float a, float b, float c, float d) {
  u32x2 r;
#if __has_builtin(__builtin_amdgcn_cvt_pk_bf16_f32)
  typedef __attribute__((ext_vector_type(2))) __bf16 bf2;
  union { bf2 v; unsigned u; } lo, hi;
  lo.v = __builtin_amdgcn_cvt_pk_bf16_f32(a, b);
  hi.v = __builtin_amdgcn_cvt_pk_bf16_f32(c, d);
  r[0] = lo.u; r[1] = hi.u;
#else
  r[0] = (unsigned)f2bf(a) | ((unsigned)f2bf(b) << 16);
  r[1] = (unsigned)f2bf(c) | ((unsigned)f2bf(d) << 16);
#endif
  return r;
}

typedef __attribute__((address_space(1))) const void* gvoidp;
typedef __attribute__((address_space(3))) void* lvoidp;
#define GLOADLDS16(g, l) __builtin_amdgcn_global_load_lds((gvoidp)(g), (lvoidp)(l), 16, 0, 0)

// ---------------------------------------------------------------------------
// Kernel 1 (fused transpose + QKV projection). Q rows pre-scaled by log2(e)
// so k_attn's softmax uses bare v_exp_f32 (2^x). Unchanged (proven).
__global__ __launch_bounds__(256) void k_proj(const float* __restrict__ x,
    const float* __restrict__ w1, const float* __restrict__ b1,
    const float* __restrict__ w2, const float* __restrict__ b2,
    const float* __restrict__ w3, const float* __restrict__ b3,
    unsigned short* __restrict__ Q, unsigned short* __restrict__ K,
    unsigned short* __restrict__ V) {
  __shared__ unsigned short xs[32][264];  // [n][c], +8 pad
  const int n0 = blockIdx.x * 32, b = blockIdx.y;
  const int t = threadIdx.x, lane = t & 63, wave = t >> 6;
  const int col = lane & 15, quad = lane >> 4;
  const float* xb = x + (size_t)b * NC * NSP;
#pragma unroll
  for (int p = 0; p < 8; ++p) {
    const int crow = (t >> 3) + p * 32;     // 0..255
    const int n4 = (t & 7) * 4;             // 0..28
    float4 v = *(const float4*)(xb + (size_t)crow * NSP + n0 + n4);
    xs[n4 + 0][crow] = f2bf(v.x);
    xs[n4 + 1][crow] = f2bf(v.y);
    xs[n4 + 2][crow] = f2bf(v.z);
    xs[n4 + 3][crow] = f2bf(v.w);
  }
  __syncthreads();
  const f32x4 zero4 = {0.f, 0.f, 0.f, 0.f};
  f32x4 acc[5][2];
#pragma unroll
  for (int i = 0; i < 5; ++i)
#pragma unroll
    for (int j = 0; j < 2; ++j) acc[i][j] = zero4;

  for (int kc = 0; kc < 8; ++kc) {
    short8 bf[2];
#pragma unroll
    for (int nt = 0; nt < 2; ++nt)
      bf[nt] = *(const short8*)&xs[nt * 16 + col][kc * 32 + quad * 8];
#pragma unroll
    for (int ml = 0; ml < 5; ++ml) {
      const int m0 = (wave * 5 + ml) * 16;
      const float* wbase; int roff;
      if (m0 < 32)      { wbase = w1; roff = m0; }
      else if (m0 < 64) { wbase = w2; roff = m0 - 32; }
      else              { wbase = w3; roff = m0 - 64; }
      const float* wp = wbase + (size_t)(roff + col) * NC + kc * 32 + quad * 8;
      float4 f0 = *(const float4*)wp;
      float4 f1 = *(const float4*)(wp + 4);
      short8 af;
      af[0] = f2bf(f0.x); af[1] = f2bf(f0.y); af[2] = f2bf(f0.z); af[3] = f2bf(f0.w);
      af[4] = f2bf(f1.x); af[5] = f2bf(f1.y); af[6] = f2bf(f1.z); af[7] = f2bf(f1.w);
#pragma unroll
      for (int nt = 0; nt < 2; ++nt)
        acc[ml][nt] = __builtin_amdgcn_mfma_f32_16x16x32_bf16(af, bf[nt], acc[ml][nt], 0, 0, 0);
    }
  }
#pragma unroll
  for (int ml = 0; ml < 5; ++ml) {
    const int m0 = (wave * 5 + ml) * 16;
    const float* bias;
    if (m0 < 32)      bias = b1 + m0;
    else if (m0 < 64) bias = b2 + (m0 - 32);
    else              bias = b3 + (m0 - 64);
    float bv[4];
#pragma unroll
    for (int r = 0; r < 4; ++r) bv[r] = bias[quad * 4 + r];
    if (m0 < 64) {  // Q or K : [b][n][32]
      unsigned short* dst = (m0 < 32) ? Q : K;
      const float scl = (m0 < 32) ? LOG2E : 1.0f;  // fold log2e into Q
      const int d0 = (m0 & 31) + quad * 4;
#pragma unroll
      for (int nt = 0; nt < 2; ++nt) {
        const int n = n0 + nt * 16 + col;
        us4 pk;
#pragma unroll
        for (int r = 0; r < 4; ++r) pk[r] = f2bf((acc[ml][nt][r] + bv[r]) * scl);
        *(us4*)(dst + ((size_t)b * NSP + n) * NCR + d0) = pk;
      }
    } else {        // V : [b][c][n]
      const int cbase = m0 - 64 + quad * 4;
#pragma unroll
      for (int nt = 0; nt < 2; ++nt) {
        const int n = n0 + nt * 16 + col;
#pragma unroll
        for (int r = 0; r < 4; ++r)
          V[((size_t)b * NC + cbase + r) * NSP + n] = f2bf(acc[ml][nt][r] + bv[r]);
      }
    }
  }
}

// ---------------------------------------------------------------------------
// Kernel 2 (fused attention) — occupancy restructure:
//   block = 32 i-rows (2 waves x 16) x 64-ch quarter, 128 threads.
//   LDS = Vs 2x[64c][64j] (16 KB, 16B-chunk XOR swizzle, gload_lds-staged)
//       + Ps single-buffer per wave [16i][64j] w/ same XOR swizzle (4 KB)
//       = 20480 B exactly -> 8 blocks/CU = 16 waves/CU (was 9).
//   Ps single-buffering is safe: Ps is wave-private; PV reads precede the
//   scores overwrite in program order and DS ops of a wave execute in order.
//   Cost: scores/exp duplicated 4x across ch-quarters (was 2x) — traded for
//   ~1.8x the latency-hiding waves.
//   Grid = 2304 blocks, batch-per-XCD chunked swizzle (lin%8 -> one batch):
//   per-XCD working set K+Q+V = ~1.5 MB, L2-resident; V fetched ~once.
__global__ __launch_bounds__(128, 4) void k_attn(const unsigned short* __restrict__ Q,
    const unsigned short* __restrict__ K, const unsigned short* __restrict__ V,
    const float* __restrict__ feat, const float* __restrict__ gamma,
    float* __restrict__ out) {
  __shared__ __align__(16) unsigned short smem[10240];  // 20480 B
  unsigned short* Vs = smem;           // [2 buf][8 q][512] : 2 x 4096 u16
  unsigned short* Ps = smem + 8192;    // [2 waves][16 i][64 j] swizzled
  // chunked XCD swizzle: xcd = lin%8 gets sw in [xcd*288, xcd*288+288) = batch xcd
  const int lin = blockIdx.x;
  const int sw = (lin & 7) * 288 + (lin >> 3);
  const int i0 = (sw % 72) * 32;
  const int ch = ((sw / 72) & 3) * 64;
  const int b  = sw / 288;
  const int t = threadIdx.x, lane = t & 63, wave = t >> 6;  // wave 0..1
  const int col = lane & 15, quad = lane >> 4;
  const int c7 = col & 7;
  const int iw = i0 + wave * 16;
  const unsigned short* Qb = Q + (size_t)b * NSP * NCR;
  const unsigned short* Kb = K + (size_t)b * NSP * NCR;
  const unsigned short* Vb = V + (size_t)b * NC * NSP;
  unsigned short* PsW = Ps + wave * 1024;

  const short8 qa = *(const short8*)(Qb + (size_t)(iw + col) * NCR + quad * 8);
  const f32x4 zero4 = {0.f, 0.f, 0.f, 0.f};
  f32x4 acc[4];
#pragma unroll
  for (int ct = 0; ct < 4; ++ct) acc[ct] = zero4;
  float rs = 0.f;  // partial row-sum for i = col (this lane's quad's j-subset)
  // staging lane map: call q covers c-rows q*8..q*8+7 (8 rows x 8 chunks of 16B);
  // lane -> row r8 = lane>>3, phys chunk pc = lane&7 holding logical chunk pc^r8.
  const int r8 = lane >> 3, pc = lane & 7, jcs = pc ^ r8;

  // ---- prologue: kb(0), stage(0) -> buf0, scores(0) -> Ps
  short8 kb[4];
#pragma unroll
  for (int mt = 0; mt < 4; ++mt)
    kb[mt] = *(const short8*)(Kb + (size_t)(mt * 16 + col) * NCR + quad * 8);
#pragma unroll
  for (int cix = 0; cix < 4; ++cix) {
    const int q = wave * 4 + cix;          // 0..7, all active
    const unsigned short* g = Vb + (size_t)(ch + q * 8 + r8) * NSP + jcs * 8;
    GLOADLDS16(g, Vs + q * 512);
  }
#pragma unroll
  for (int mt = 0; mt < 4; ++mt) {
    f32x4 s = __builtin_amdgcn_mfma_f32_16x16x32_bf16(kb[mt], qa, zero4, 0, 0, 0);
    const float e0 = fexp2(s[0]), e1 = fexp2(s[1]), e2 = fexp2(s[2]), e3 = fexp2(s[3]);
    rs += (e0 + e1) + (e2 + e3);
    *(u32x2*)(PsW + col * 64 + ((((mt << 1) | (quad >> 1)) ^ c7) << 3) +
              ((quad & 1) << 2)) = pack4bf(e0, e1, e2, e3);
  }

  // ---- main loop: one barrier per iteration
  for (int kc = 0; kc < 36; ++kc) {
    __syncthreads();  // Vs(kc) staged (vmcnt drained)
    const int bufc = kc & 1, bufn = bufc ^ 1;
    const int j1 = (kc + 1) * 64;
    const bool more = (kc + 1 < 36);
    if (more) {
      // kb(n+1) first (in-order vmcnt: retires before the staging loads)
#pragma unroll
      for (int mt = 0; mt < 4; ++mt)
        kb[mt] = *(const short8*)(Kb + (size_t)(j1 + mt * 16 + col) * NCR + quad * 8);
      // stage(n+1) -> Vs bufn (full PV+scores distance to drain before barrier)
#pragma unroll
      for (int cix = 0; cix < 4; ++cix) {
        const int q = wave * 4 + cix;
        const unsigned short* g = Vb + (size_t)(ch + q * 8 + r8) * NSP + j1 + jcs * 8;
        GLOADLDS16(g, Vs + bufn * 4096 + q * 512);
      }
    }
    // PV(kc): reads Ps (written last iter by this wave) + Vs bufc
    const unsigned short* vsc = Vs + bufc * 4096;
#pragma unroll
    for (int kk = 0; kk < 2; ++kk) {
      const int pc16 = ((((kk << 2) | quad)) ^ c7) << 3;  // swizzled 16B chunk off
      const short8 pa = *(const short8*)(PsW + col * 64 + pc16);
#pragma unroll
      for (int ct = 0; ct < 4; ++ct) {
        const short8 vbf = *(const short8*)(vsc + (ct * 16 + col) * 64 + pc16);
        acc[ct] = __builtin_amdgcn_mfma_f32_16x16x32_bf16(pa, vbf, acc[ct], 0, 0, 0);
      }
    }
    if (more) {
      // scores(n+1) -> Ps (single buffer: overwrite AFTER this iter's PV reads;
      // wave-private + in-order DS makes this safe)
#pragma unroll
      for (int mt = 0; mt < 4; ++mt) {
        f32x4 s = __builtin_amdgcn_mfma_f32_16x16x32_bf16(kb[mt], qa, zero4, 0, 0, 0);
        const float e0 = fexp2(s[0]), e1 = fexp2(s[1]), e2 = fexp2(s[2]), e3 = fexp2(s[3]);
        rs += (e0 + e1) + (e2 + e3);
        *(u32x2*)(PsW + col * 64 + ((((mt << 1) | (quad >> 1)) ^ c7) << 3) +
                  ((quad & 1) << 2)) = pack4bf(e0, e1, e2, e3);
      }
    }
  }

  // ---- l: sum the 4 quads of each col (full row-sum for i = col), then
  // redistribute to D-layout rows (i = quad*4 + r) for the epilogue.
  rs += __shfl_xor(rs, 16, 64);
  rs += __shfl_xor(rs, 32, 64);
  const float g = gamma[0];
  float rinv[4];
#pragma unroll
  for (int r = 0; r < 4; ++r) rinv[r] = g / __shfl(rs, quad * 4 + r, 64);

  // ---- epilogue: float4 over r (i-contiguous), 64B segments
  const float* fb = feat + (size_t)b * NC * NSP;
  float* ob = out + (size_t)b * NC * NSP;
#pragma unroll
  for (int ct = 0; ct < 4; ++ct) {
    const size_t a0 = (size_t)(ch + ct * 16 + col) * NSP + iw + quad * 4;
    float4 f = *(const float4*)(fb + a0);
    float4 o;
    o.x = acc[ct][0] * rinv[0] + f.x;
    o.y = acc[ct][1] * rinv[1] + f.y;
    o.z = acc[ct][2] * rinv[2] + f.z;
    o.w = acc[ct][3] * rinv[3] + f.w;
    *(float4*)(ob + a0) = o;
  }
}

// ---------------------------------------------------------------------------
// Workspace layout (bytes), total 11,796,480 (~11.3 MB):
//   Q : [0, 1179648)            bf16 [8][2304][32]   (pre-scaled by log2e)
//   K : [1179648, 2359296)      bf16 [8][2304][32]
//   V : [2359296, 11796480)     bf16 [8][256][2304]
#define OFF_Q  0UL
#define OFF_K  1179648UL
#define OFF_V  2359296UL

extern "C" void kernel_launch(void* const* d_in, const int* in_sizes, int n_in,
                              void* d_out, int out_size, void* d_ws, size_t ws_size,
                              hipStream_t stream) {
  const float* feat  = (const float*)d_in[0];
  const float* w1    = (const float*)d_in[1];
  const float* b1    = (const float*)d_in[2];
  const float* w2    = (const float*)d_in[3];
  const float* b2    = (const float*)d_in[4];
  const float* w3    = (const float*)d_in[5];
  const float* b3    = (const float*)d_in[6];
  const float* gamma = (const float*)d_in[7];
  float* out = (float*)d_out;
  char* ws = (char*)d_ws;
  unsigned short* Q = (unsigned short*)(ws + OFF_Q);
  unsigned short* K = (unsigned short*)(ws + OFF_K);
  unsigned short* V = (unsigned short*)(ws + OFF_V);

  hipLaunchKernelGGL(k_proj, dim3(72, NB), dim3(256), 0, stream,
                     feat, w1, b1, w2, b2, w3, b3, Q, K, V);
  hipLaunchKernelGGL(k_attn, dim3(2304), dim3(128), 0, stream,
                     Q, K, V, feat, gamma, out);
}

// Round 2
// 192.312 us; speedup vs baseline: 1.0115x; 1.0115x over previous
//
#include <hip/hip_runtime.h>
#include <stdint.h>

// Problem constants (B,C,H,W = 8,256,48,48)
#define NB  8
#define NC  256
#define NCR 32
#define NSP 2304  // N = H*W
#define LOG2E 1.44269504088896340736f

typedef __attribute__((ext_vector_type(8))) short short8;   // 8 x bf16 (4 VGPRs)
typedef __attribute__((ext_vector_type(4))) float f32x4;    // MFMA C/D frag
typedef __attribute__((ext_vector_type(4))) unsigned short us4;
typedef __attribute__((ext_vector_type(2))) unsigned int u32x2;

__device__ __forceinline__ unsigned short f2bf(float f) {
  union { float f; unsigned u; } a; a.f = f;
  unsigned r = (a.u + 0x7FFFu + ((a.u >> 16) & 1u)) >> 16;  // RNE
  return (unsigned short)r;
}

__device__ __forceinline__ float fexp2(float x) {
#if __has_builtin(__builtin_amdgcn_exp2f)
  return __builtin_amdgcn_exp2f(x);
#else
  return __exp2f(x);
#endif
}

// pack 4 fp32 -> 4 bf16 (RNE) as two dwords
__device__ __forceinline__ u32x2 pack4bf(float a, float b, float c, float d) {
  u32x2 r;
#if __has_builtin(__builtin_amdgcn_cvt_pk_bf16_f32)
  typedef __attribute__((ext_vector_type(2))) __bf16 bf2;
  union { bf2 v; unsigned u; } lo, hi;
  lo.v = __builtin_amdgcn_cvt_pk_bf16_f32(a, b);
  hi.v = __builtin_amdgcn_cvt_pk_bf16_f32(c, d);
  r[0] = lo.u; r[1] = hi.u;
#else
  r[0] = (unsigned)f2bf(a) | ((unsigned)f2bf(b) << 16);
  r[1] = (unsigned)f2bf(c) | ((unsigned)f2bf(d) << 16);
#endif
  return r;
}

typedef __attribute__((address_space(1))) const void* gvoidp;
typedef __attribute__((address_space(3))) void* lvoidp;
#define GLOADLDS16(g, l) __builtin_amdgcn_global_load_lds((gvoidp)(g), (lvoidp)(l), 16, 0, 0)

// ---------------------------------------------------------------------------
// Kernel 1 (fused transpose + QKV projection). Q rows pre-scaled by log2(e)
// so k_attn's softmax uses bare v_exp_f32 (2^x). Unchanged (proven).
__global__ __launch_bounds__(256) void k_proj(const float* __restrict__ x,
    const float* __restrict__ w1, const float* __restrict__ b1,
    const float* __restrict__ w2, const float* __restrict__ b2,
    const float* __restrict__ w3, const float* __restrict__ b3,
    unsigned short* __restrict__ Q, unsigned short* __restrict__ K,
    unsigned short* __restrict__ V) {
  __shared__ unsigned short xs[32][264];  // [n][c], +8 pad
  const int n0 = blockIdx.x * 32, b = blockIdx.y;
  const int t = threadIdx.x, lane = t & 63, wave = t >> 6;
  const int col = lane & 15, quad = lane >> 4;
  const float* xb = x + (size_t)b * NC * NSP;
#pragma unroll
  for (int p = 0; p < 8; ++p) {
    const int crow = (t >> 3) + p * 32;     // 0..255
    const int n4 = (t & 7) * 4;             // 0..28
    float4 v = *(const float4*)(xb + (size_t)crow * NSP + n0 + n4);
    xs[n4 + 0][crow] = f2bf(v.x);
    xs[n4 + 1][crow] = f2bf(v.y);
    xs[n4 + 2][crow] = f2bf(v.z);
    xs[n4 + 3][crow] = f2bf(v.w);
  }
  __syncthreads();
  const f32x4 zero4 = {0.f, 0.f, 0.f, 0.f};
  f32x4 acc[5][2];
#pragma unroll
  for (int i = 0; i < 5; ++i)
#pragma unroll
    for (int j = 0; j < 2; ++j) acc[i][j] = zero4;

  for (int kc = 0; kc < 8; ++kc) {
    short8 bf[2];
#pragma unroll
    for (int nt = 0; nt < 2; ++nt)
      bf[nt] = *(const short8*)&xs[nt * 16 + col][kc * 32 + quad * 8];
#pragma unroll
    for (int ml = 0; ml < 5; ++ml) {
      const int m0 = (wave * 5 + ml) * 16;
      const float* wbase; int roff;
      if (m0 < 32)      { wbase = w1; roff = m0; }
      else if (m0 < 64) { wbase = w2; roff = m0 - 32; }
      else              { wbase = w3; roff = m0 - 64; }
      const float* wp = wbase + (size_t)(roff + col) * NC + kc * 32 + quad * 8;
      float4 f0 = *(const float4*)wp;
      float4 f1 = *(const float4*)(wp + 4);
      short8 af;
      af[0] = f2bf(f0.x); af[1] = f2bf(f0.y); af[2] = f2bf(f0.z); af[3] = f2bf(f0.w);
      af[4] = f2bf(f1.x); af[5] = f2bf(f1.y); af[6] = f2bf(f1.z); af[7] = f2bf(f1.w);
#pragma unroll
      for (int nt = 0; nt < 2; ++nt)
        acc[ml][nt] = __builtin_amdgcn_mfma_f32_16x16x32_bf16(af, bf[nt], acc[ml][nt], 0, 0, 0);
    }
  }
#pragma unroll
  for (int ml = 0; ml < 5; ++ml) {
    const int m0 = (wave * 5 + ml) * 16;
    const float* bias;
    if (m0 < 32)      bias = b1 + m0;
    else if (m0 < 64) bias = b2 + (m0 - 32);
    else              bias = b3 + (m0 - 64);
    float bv[4];
#pragma unroll
    for (int r = 0; r < 4; ++r) bv[r] = bias[quad * 4 + r];
    if (m0 < 64) {  // Q or K : [b][n][32]
      unsigned short* dst = (m0 < 32) ? Q : K;
      const float scl = (m0 < 32) ? LOG2E : 1.0f;  // fold log2e into Q
      const int d0 = (m0 & 31) + quad * 4;
#pragma unroll
      for (int nt = 0; nt < 2; ++nt) {
        const int n = n0 + nt * 16 + col;
        us4 pk;
#pragma unroll
        for (int r = 0; r < 4; ++r) pk[r] = f2bf((acc[ml][nt][r] + bv[r]) * scl);
        *(us4*)(dst + ((size_t)b * NSP + n) * NCR + d0) = pk;
      }
    } else {        // V : [b][c][n]
      const int cbase = m0 - 64 + quad * 4;
#pragma unroll
      for (int nt = 0; nt < 2; ++nt) {
        const int n = n0 + nt * 16 + col;
#pragma unroll
        for (int r = 0; r < 4; ++r)
          V[((size_t)b * NC + cbase + r) * NSP + n] = f2bf(acc[ml][nt][r] + bv[r]);
      }
    }
  }
}

// ---------------------------------------------------------------------------
// Kernel 2 (fused attention) — shared-scores, 6-wave restructure of the proven
// R0 geometry (48 i x 128 ch, grid 768 = 3 blocks/CU exactly, zero tail):
//   6 waves = 3 i-groups (ig) x 2 ch-halves (wq). Only wq==0 waves compute
//   scores/exp for their 16 i-rows and publish P (bf16, XOR-swizzled) to a
//   cross-wave DOUBLE-buffered Ps; the wq==1 partner does PV only.
//   -> total scores/exp/K-load work IDENTICAL to R0, PV work identical,
//      but 18 waves/CU instead of 9 (LDS 45.2 KB -> still 3 blocks/CU).
//   Vs: same 16B-chunk XOR swizzle (phys = logical ^ (c&7)), gload_lds-staged
//   by all 6 waves (16 calls of 1KB each per buffer).
//   One barrier per iteration protects both Vs(kc) staging and Ps(kc) writes.
__global__ __launch_bounds__(384, 5) void k_attn(const unsigned short* __restrict__ Q,
    const unsigned short* __restrict__ K, const unsigned short* __restrict__ V,
    const float* __restrict__ feat, const float* __restrict__ gamma,
    float* __restrict__ out) {
  __shared__ __align__(16) unsigned short smem[22624];  // 45,248 B
  unsigned short* Vs = smem;            // [2 buf][128 c][64 j] : 2 x 8192 u16
  unsigned short* Ps = smem + 16384;    // [3 ig][2 buf][16 i][64 j] swizzled
  float* rsum = (float*)(smem + 22528); // [48] row sums (3 ig x 16 i)
  // batch-per-XCD swizzle: 768 = 8 b x 96; lin&7 -> batch (one batch per XCD)
  const int lin = blockIdx.x;
  const int b = lin & 7;
  const int rest = lin >> 3;            // 0..95
  const int i0 = (rest % 48) * 48;
  const int ch = (rest / 48) * 128;
  const int t = threadIdx.x, lane = t & 63, wave = t >> 6;  // wave 0..5
  const int ig = wave >> 1, wq = wave & 1;
  const bool sc = (wq == 0);            // scores-duty wave
  const int col = lane & 15, quad = lane >> 4;
  const int c7 = col & 7;
  const int iw = i0 + ig * 16;
  const unsigned short* Qb = Q + (size_t)b * NSP * NCR;
  const unsigned short* Kb = K + (size_t)b * NSP * NCR;
  const unsigned short* Vb = V + (size_t)b * NC * NSP;
  unsigned short* PsIG = Ps + ig * 2048;  // 2 bufs x 1024

  const short8 qa = *(const short8*)(Qb + (size_t)(iw + col) * NCR + quad * 8);
  const f32x4 zero4 = {0.f, 0.f, 0.f, 0.f};
  f32x4 acc[4];
#pragma unroll
  for (int ct = 0; ct < 4; ++ct) acc[ct] = zero4;
  float rs = 0.f;  // partial row-sum for i = col (scores waves only)
  // staging lane map: call cq covers c-rows cq*8..cq*8+7 (8 rows x 8 chunks of
  // 16B); lane -> row r8 = lane>>3, phys chunk pc = lane&7 holds logical pc^r8.
  const int r8 = lane >> 3, pc = lane & 7, jcs = pc ^ r8;

  // ---- prologue: kb(0), stage(0) -> buf0, scores(0) -> Ps buf0
  short8 kb[4];
  if (sc) {
#pragma unroll
    for (int mt = 0; mt < 4; ++mt)
      kb[mt] = *(const short8*)(Kb + (size_t)(mt * 16 + col) * NCR + quad * 8);
  }
#pragma unroll
  for (int cix = 0; cix < 3; ++cix) {
    const int cq = wave * 3 + cix;        // 0..17; cq>=16 skipped (wave-uniform)
    if (cq < 16) {
      const unsigned short* g = Vb + (size_t)(ch + cq * 8 + r8) * NSP + jcs * 8;
      GLOADLDS16(g, Vs + cq * 512);
    }
  }
  if (sc) {
#pragma unroll
    for (int mt = 0; mt < 4; ++mt) {
      f32x4 s = __builtin_amdgcn_mfma_f32_16x16x32_bf16(kb[mt], qa, zero4, 0, 0, 0);
      const float e0 = fexp2(s[0]), e1 = fexp2(s[1]), e2 = fexp2(s[2]), e3 = fexp2(s[3]);
      rs += (e0 + e1) + (e2 + e3);
      *(u32x2*)(PsIG + col * 64 + ((((mt << 1) | (quad >> 1)) ^ c7) << 3) +
                ((quad & 1) << 2)) = pack4bf(e0, e1, e2, e3);
    }
  }

  // ---- main loop: one barrier per iteration
  for (int kc = 0; kc < 36; ++kc) {
    __syncthreads();  // Vs(kc) staged (vmcnt drained), Ps(kc) visible
    const int bufc = kc & 1, bufn = bufc ^ 1;
    const int j1 = (kc + 1) * 64;
    const bool more = (kc + 1 < 36);
    if (more) {
      if (sc) {
        // kb(n+1) first (in-order vmcnt: retires before the staging loads)
#pragma unroll
        for (int mt = 0; mt < 4; ++mt)
          kb[mt] = *(const short8*)(Kb + (size_t)(j1 + mt * 16 + col) * NCR + quad * 8);
      }
      // stage(n+1) -> Vs bufn (full PV+scores distance to drain before barrier)
#pragma unroll
      for (int cix = 0; cix < 3; ++cix) {
        const int cq = wave * 3 + cix;
        if (cq < 16) {
          const unsigned short* g = Vb + (size_t)(ch + cq * 8 + r8) * NSP + j1 + jcs * 8;
          GLOADLDS16(g, Vs + bufn * 8192 + cq * 512);
        }
      }
    }
    // PV(kc): reads Ps[ig][bufc] (published by the ig's score wave) + Vs bufc
    const unsigned short* vsc = Vs + bufc * 8192;
    const unsigned short* psc = PsIG + bufc * 1024;
#pragma unroll
    for (int kk = 0; kk < 2; ++kk) {
      const int pc16 = ((((kk << 2) | quad)) ^ c7) << 3;  // swizzled 16B chunk
      const short8 pa = *(const short8*)(psc + col * 64 + pc16);
#pragma unroll
      for (int ct = 0; ct < 4; ++ct) {
        const short8 vbf = *(const short8*)(vsc + (wq * 64 + ct * 16 + col) * 64 + pc16);
        acc[ct] = __builtin_amdgcn_mfma_f32_16x16x32_bf16(pa, vbf, acc[ct], 0, 0, 0);
      }
    }
    if (more && sc) {
      // scores(n+1) -> Ps[ig][bufn]; visible to partner wave after next barrier
      unsigned short* pwn = PsIG + bufn * 1024;
#pragma unroll
      for (int mt = 0; mt < 4; ++mt) {
        f32x4 s = __builtin_amdgcn_mfma_f32_16x16x32_bf16(kb[mt], qa, zero4, 0, 0, 0);
        const float e0 = fexp2(s[0]), e1 = fexp2(s[1]), e2 = fexp2(s[2]), e3 = fexp2(s[3]);
        rs += (e0 + e1) + (e2 + e3);
        *(u32x2*)(pwn + col * 64 + ((((mt << 1) | (quad >> 1)) ^ c7) << 3) +
                  ((quad & 1) << 2)) = pack4bf(e0, e1, e2, e3);
      }
    }
  }

  // ---- row sums: score wave reduces quads (full row-sum for i = col) and
  // publishes to LDS; all waves read for the epilogue scaling.
  if (sc) {
    rs += __shfl_xor(rs, 16, 64);
    rs += __shfl_xor(rs, 32, 64);
    if (lane < 16) rsum[ig * 16 + lane] = rs;
  }
  __syncthreads();
  const float g = gamma[0];
  float rinv[4];
#pragma unroll
  for (int r = 0; r < 4; ++r) rinv[r] = g / rsum[ig * 16 + quad * 4 + r];

  // ---- epilogue: float4 over r (i-contiguous), 64B segments
  const float* fb = feat + (size_t)b * NC * NSP;
  float* ob = out + (size_t)b * NC * NSP;
#pragma unroll
  for (int ct = 0; ct < 4; ++ct) {
    const size_t a0 = (size_t)(ch + wq * 64 + ct * 16 + col) * NSP + iw + quad * 4;
    float4 f = *(const float4*)(fb + a0);
    float4 o;
    o.x = acc[ct][0] * rinv[0] + f.x;
    o.y = acc[ct][1] * rinv[1] + f.y;
    o.z = acc[ct][2] * rinv[2] + f.z;
    o.w = acc[ct][3] * rinv[3] + f.w;
    *(float4*)(ob + a0) = o;
  }
}

// ---------------------------------------------------------------------------
// Workspace layout (bytes), total 11,796,480 (~11.3 MB):
//   Q : [0, 1179648)            bf16 [8][2304][32]   (pre-scaled by log2e)
//   K : [1179648, 2359296)      bf16 [8][2304][32]
//   V : [2359296, 11796480)     bf16 [8][256][2304]
#define OFF_Q  0UL
#define OFF_K  1179648UL
#define OFF_V  2359296UL

extern "C" void kernel_launch(void* const* d_in, const int* in_sizes, int n_in,
                              void* d_out, int out_size, void* d_ws, size_t ws_size,
                              hipStream_t stream) {
  const float* feat  = (const float*)d_in[0];
  const float* w1    = (const float*)d_in[1];
  const float* b1    = (const float*)d_in[2];
  const float* w2    = (const float*)d_in[3];
  const float* b2    = (const float*)d_in[4];
  const float* w3    = (const float*)d_in[5];
  const float* b3    = (const float*)d_in[6];
  const float* gamma = (const float*)d_in[7];
  float* out = (float*)d_out;
  char* ws = (char*)d_ws;
  unsigned short* Q = (unsigned short*)(ws + OFF_Q);
  unsigned short* K = (unsigned short*)(ws + OFF_K);
  unsigned short* V = (unsigned short*)(ws + OFF_V);

  hipLaunchKernelGGL(k_proj, dim3(72, NB), dim3(256), 0, stream,
                     feat, w1, b1, w2, b2, w3, b3, Q, K, V);
  hipLaunchKernelGGL(k_attn, dim3(768), dim3(384), 0, stream,
                     Q, K, V, feat, gamma, out);
}

// Round 3
// 168.153 us; speedup vs baseline: 1.1568x; 1.1437x over previous
//
#include <hip/hip_runtime.h>
#include <stdint.h>

// Problem constants (B,C,H,W = 8,256,48,48)
#define NB  8
#define NC  256
#define NCR 32
#define NSP 2304  // N = H*W
#define LOG2E 1.44269504088896340736f

typedef __attribute__((ext_vector_type(8))) short short8;   // 8 x bf16 (4 VGPRs)
typedef __attribute__((ext_vector_type(4))) float f32x4;    // MFMA C/D frag
typedef __attribute__((ext_vector_type(4))) unsigned short us4;
typedef __attribute__((ext_vector_type(2))) unsigned int u32x2;

__device__ __forceinline__ unsigned short f2bf(float f) {
  union { float f; unsigned u; } a; a.f = f;
  unsigned r = (a.u + 0x7FFFu + ((a.u >> 16) & 1u)) >> 16;  // RNE
  return (unsigned short)r;
}

__device__ __forceinline__ float fexp2(float x) {
#if __has_builtin(__builtin_amdgcn_exp2f)
  return __builtin_amdgcn_exp2f(x);
#else
  return __exp2f(x);
#endif
}

// pack 4 fp32 -> 4 bf16 (RNE) as two dwords
__device__ __forceinline__ u32x2 pack4bf(float a, float b, float c, float d) {
  u32x2 r;
#if __has_builtin(__builtin_amdgcn_cvt_pk_bf16_f32)
  typedef __attribute__((ext_vector_type(2))) __bf16 bf2;
  union { bf2 v; unsigned u; } lo, hi;
  lo.v = __builtin_amdgcn_cvt_pk_bf16_f32(a, b);
  hi.v = __builtin_amdgcn_cvt_pk_bf16_f32(c, d);
  r[0] = lo.u; r[1] = hi.u;
#else
  r[0] = (unsigned)f2bf(a) | ((unsigned)f2bf(b) << 16);
  r[1] = (unsigned)f2bf(c) | ((unsigned)f2bf(d) << 16);
#endif
  return r;
}

typedef __attribute__((address_space(1))) const void* gvoidp;
typedef __attribute__((address_space(3))) void* lvoidp;
#define GLOADLDS16(g, l) __builtin_amdgcn_global_load_lds((gvoidp)(g), (lvoidp)(l), 16, 0, 0)

// ---------------------------------------------------------------------------
// Kernel 1 (fused transpose + QKV projection). Q rows pre-scaled by log2(e)
// so k_attn's softmax uses bare v_exp_f32 (2^x). Unchanged (proven).
__global__ __launch_bounds__(256) void k_proj(const float* __restrict__ x,
    const float* __restrict__ w1, const float* __restrict__ b1,
    const float* __restrict__ w2, const float* __restrict__ b2,
    const float* __restrict__ w3, const float* __restrict__ b3,
    unsigned short* __restrict__ Q, unsigned short* __restrict__ K,
    unsigned short* __restrict__ V) {
  __shared__ unsigned short xs[32][264];  // [n][c], +8 pad
  const int n0 = blockIdx.x * 32, b = blockIdx.y;
  const int t = threadIdx.x, lane = t & 63, wave = t >> 6;
  const int col = lane & 15, quad = lane >> 4;
  const float* xb = x + (size_t)b * NC * NSP;
#pragma unroll
  for (int p = 0; p < 8; ++p) {
    const int crow = (t >> 3) + p * 32;     // 0..255
    const int n4 = (t & 7) * 4;             // 0..28
    float4 v = *(const float4*)(xb + (size_t)crow * NSP + n0 + n4);
    xs[n4 + 0][crow] = f2bf(v.x);
    xs[n4 + 1][crow] = f2bf(v.y);
    xs[n4 + 2][crow] = f2bf(v.z);
    xs[n4 + 3][crow] = f2bf(v.w);
  }
  __syncthreads();
  const f32x4 zero4 = {0.f, 0.f, 0.f, 0.f};
  f32x4 acc[5][2];
#pragma unroll
  for (int i = 0; i < 5; ++i)
#pragma unroll
    for (int j = 0; j < 2; ++j) acc[i][j] = zero4;

  for (int kc = 0; kc < 8; ++kc) {
    short8 bf[2];
#pragma unroll
    for (int nt = 0; nt < 2; ++nt)
      bf[nt] = *(const short8*)&xs[nt * 16 + col][kc * 32 + quad * 8];
#pragma unroll
    for (int ml = 0; ml < 5; ++ml) {
      const int m0 = (wave * 5 + ml) * 16;
      const float* wbase; int roff;
      if (m0 < 32)      { wbase = w1; roff = m0; }
      else if (m0 < 64) { wbase = w2; roff = m0 - 32; }
      else              { wbase = w3; roff = m0 - 64; }
      const float* wp = wbase + (size_t)(roff + col) * NC + kc * 32 + quad * 8;
      float4 f0 = *(const float4*)wp;
      float4 f1 = *(const float4*)(wp + 4);
      short8 af;
      af[0] = f2bf(f0.x); af[1] = f2bf(f0.y); af[2] = f2bf(f0.z); af[3] = f2bf(f0.w);
      af[4] = f2bf(f1.x); af[5] = f2bf(f1.y); af[6] = f2bf(f1.z); af[7] = f2bf(f1.w);
#pragma unroll
      for (int nt = 0; nt < 2; ++nt)
        acc[ml][nt] = __builtin_amdgcn_mfma_f32_16x16x32_bf16(af, bf[nt], acc[ml][nt], 0, 0, 0);
    }
  }
#pragma unroll
  for (int ml = 0; ml < 5; ++ml) {
    const int m0 = (wave * 5 + ml) * 16;
    const float* bias;
    if (m0 < 32)      bias = b1 + m0;
    else if (m0 < 64) bias = b2 + (m0 - 32);
    else              bias = b3 + (m0 - 64);
    float bv[4];
#pragma unroll
    for (int r = 0; r < 4; ++r) bv[r] = bias[quad * 4 + r];
    if (m0 < 64) {  // Q or K : [b][n][32]
      unsigned short* dst = (m0 < 32) ? Q : K;
      const float scl = (m0 < 32) ? LOG2E : 1.0f;  // fold log2e into Q
      const int d0 = (m0 & 31) + quad * 4;
#pragma unroll
      for (int nt = 0; nt < 2; ++nt) {
        const int n = n0 + nt * 16 + col;
        us4 pk;
#pragma unroll
        for (int r = 0; r < 4; ++r) pk[r] = f2bf((acc[ml][nt][r] + bv[r]) * scl);
        *(us4*)(dst + ((size_t)b * NSP + n) * NCR + d0) = pk;
      }
    } else {        // V : [b][c][n]
      const int cbase = m0 - 64 + quad * 4;
#pragma unroll
      for (int nt = 0; nt < 2; ++nt) {
        const int n = n0 + nt * 16 + col;
#pragma unroll
        for (int r = 0; r < 4; ++r)
          V[((size_t)b * NC + cbase + r) * NSP + n] = f2bf(acc[ml][nt][r] + bv[r]);
      }
    }
  }
}

// ---------------------------------------------------------------------------
// Kernel 2 (fused attention) — R0 structure (proven best: 48i x 128ch, 3 waves,
// grid 768 = 3 blocks/CU, one barrier/iter) with exactly two changes:
//  (1) batch-per-XCD swizzle (validated in R2: FETCH 54.7->16.5 MB): b = lin&7,
//      so each XCD's working set = one batch's V+K+Q = 1.47 MB, L2-resident.
//      The per-iteration vmcnt(0)+barrier drain then waits on ~L2-latency
//      staging instead of HBM/L3-latency staging.
//  (2) Ps single-buffered (wave-private: PV reads, then the SAME wave's
//      scores overwrite, in-order DS -> safe). LDS 46592 -> 39680 B =
//      4-blocks/CU capacity (absorbs dispatch skew; grid still 768).
__global__ __launch_bounds__(192) void k_attn(const unsigned short* __restrict__ Q,
    const unsigned short* __restrict__ K, const unsigned short* __restrict__ V,
    const float* __restrict__ feat, const float* __restrict__ gamma,
    float* __restrict__ out) {
  __shared__ __align__(16) unsigned short smem[19840];  // 39680 B
  unsigned short* Vs = smem;            // [buf][128 c][64 j] : 2 x 8192 u16
  unsigned short* Ps = smem + 16384;    // [wave][16 i][72] : 3 x 1152 u16
  // batch-per-XCD swizzle: lin&7 -> batch (one batch per XCD, L2-resident)
  const int lin = blockIdx.x;
  const int b = lin & 7;
  const int rest = lin >> 3;            // 0..95
  const int i0 = (rest % 48) * 48;
  const int ch = (rest / 48) * 128;
  const int t = threadIdx.x, lane = t & 63, wave = t >> 6;  // wave 0..2
  const int col = lane & 15, quad = lane >> 4;
  const int iw = i0 + wave * 16;
  const unsigned short* Qb = Q + (size_t)b * NSP * NCR;
  const unsigned short* Kb = K + (size_t)b * NSP * NCR;
  const unsigned short* Vb = V + (size_t)b * NC * NSP;
  unsigned short* PsW = Ps + wave * 1152;  // single buffer (wave-private)

  const short8 qa = *(const short8*)(Qb + (size_t)(iw + col) * NCR + quad * 8);
  const f32x4 zero4 = {0.f, 0.f, 0.f, 0.f};
  f32x4 acc[8];
#pragma unroll
  for (int ct = 0; ct < 8; ++ct) acc[ct] = zero4;
  float rs = 0.f;  // partial row-sum for i = col (this lane's quad's j-subset)
  // staging lane map: call q covers c-rows q*8..q*8+7 (8 rows x 8 chunks of 16B);
  // lane -> row r8 = lane>>3, phys chunk pc = lane&7 holding logical chunk pc^r8.
  const int r8 = lane >> 3, pc = lane & 7, jcs = pc ^ r8;

  // ---- prologue: kb(0), stage(0) -> buf0, scores(0) -> Ps
  short8 kb[4];
#pragma unroll
  for (int mt = 0; mt < 4; ++mt)
    kb[mt] = *(const short8*)(Kb + (size_t)(mt * 16 + col) * NCR + quad * 8);
#pragma unroll
  for (int cix = 0; cix < 6; ++cix) {
    const int q = wave * 6 + cix;          // 0..17; q>=16 skipped (wave-uniform)
    if (q < 16) {
      const unsigned short* g = Vb + (size_t)(ch + q * 8 + r8) * NSP + jcs * 8;
      GLOADLDS16(g, Vs + q * 512);
    }
  }
#pragma unroll
  for (int mt = 0; mt < 4; ++mt) {
    f32x4 s = __builtin_amdgcn_mfma_f32_16x16x32_bf16(kb[mt], qa, zero4, 0, 0, 0);
    const float e0 = fexp2(s[0]), e1 = fexp2(s[1]), e2 = fexp2(s[2]), e3 = fexp2(s[3]);
    rs += (e0 + e1) + (e2 + e3);
    *(u32x2*)(PsW + col * 72 + mt * 16 + quad * 4) = pack4bf(e0, e1, e2, e3);
  }

  // ---- main loop: one barrier per iteration
  for (int kc = 0; kc < 36; ++kc) {
    __syncthreads();  // Vs(kc) staged (vmcnt drained)
    const int bufc = kc & 1, bufn = bufc ^ 1;
    const int j1 = (kc + 1) * 64;
    const bool more = (kc + 1 < 36);
    if (more) {
      // kb(n+1) first (in-order vmcnt: retires before the staging loads)
#pragma unroll
      for (int mt = 0; mt < 4; ++mt)
        kb[mt] = *(const short8*)(Kb + (size_t)(j1 + mt * 16 + col) * NCR + quad * 8);
      // stage(n+1) -> Vs bufn (full PV+scores distance to drain before barrier)
#pragma unroll
      for (int cix = 0; cix < 6; ++cix) {
        const int q = wave * 6 + cix;
        if (q < 16) {
          const unsigned short* g = Vb + (size_t)(ch + q * 8 + r8) * NSP + j1 + jcs * 8;
          GLOADLDS16(g, Vs + bufn * 8192 + q * 512);
        }
      }
    }
    // PV(kc): reads Ps (this wave's, written last iter) + Vs bufc
    const unsigned short* vsc = Vs + bufc * 8192;
#pragma unroll
    for (int kk = 0; kk < 2; ++kk) {
      const short8 pa = *(const short8*)(PsW + col * 72 + kk * 32 + quad * 8);
#pragma unroll
      for (int ct = 0; ct < 8; ++ct) {
        const short8 vbf = *(const short8*)(vsc + (ct * 16 + col) * 64 +
                                            (((kk * 4 + quad) ^ (col & 7)) * 8));
        acc[ct] = __builtin_amdgcn_mfma_f32_16x16x32_bf16(pa, vbf, acc[ct], 0, 0, 0);
      }
    }
    if (more) {
      // scores(n+1) -> Ps (single buffer: overwrite AFTER this iter's PV reads;
      // wave-private + in-order DS makes this safe)
#pragma unroll
      for (int mt = 0; mt < 4; ++mt) {
        f32x4 s = __builtin_amdgcn_mfma_f32_16x16x32_bf16(kb[mt], qa, zero4, 0, 0, 0);
        const float e0 = fexp2(s[0]), e1 = fexp2(s[1]), e2 = fexp2(s[2]), e3 = fexp2(s[3]);
        rs += (e0 + e1) + (e2 + e3);
        *(u32x2*)(PsW + col * 72 + mt * 16 + quad * 4) = pack4bf(e0, e1, e2, e3);
      }
    }
  }

  // ---- l: sum the 4 quads of each col (full row-sum for i = col), then
  // redistribute to D-layout rows (i = quad*4 + r) for the epilogue.
  rs += __shfl_xor(rs, 16, 64);
  rs += __shfl_xor(rs, 32, 64);
  const float g = gamma[0];
  float rinv[4];
#pragma unroll
  for (int r = 0; r < 4; ++r) rinv[r] = g / __shfl(rs, quad * 4 + r, 64);

  // ---- epilogue: float4 over r (i-contiguous), 64B segments
  const float* fb = feat + (size_t)b * NC * NSP;
  float* ob = out + (size_t)b * NC * NSP;
#pragma unroll
  for (int ct = 0; ct < 8; ++ct) {
    const size_t a0 = (size_t)(ch + ct * 16 + col) * NSP + iw + quad * 4;
    float4 f = *(const float4*)(fb + a0);
    float4 o;
    o.x = acc[ct][0] * rinv[0] + f.x;
    o.y = acc[ct][1] * rinv[1] + f.y;
    o.z = acc[ct][2] * rinv[2] + f.z;
    o.w = acc[ct][3] * rinv[3] + f.w;
    *(float4*)(ob + a0) = o;
  }
}

// ---------------------------------------------------------------------------
// Workspace layout (bytes), total 11,796,480 (~11.3 MB):
//   Q : [0, 1179648)            bf16 [8][2304][32]   (pre-scaled by log2e)
//   K : [1179648, 2359296)      bf16 [8][2304][32]
//   V : [2359296, 11796480)     bf16 [8][256][2304]
#define OFF_Q  0UL
#define OFF_K  1179648UL
#define OFF_V  2359296UL

extern "C" void kernel_launch(void* const* d_in, const int* in_sizes, int n_in,
                              void* d_out, int out_size, void* d_ws, size_t ws_size,
                              hipStream_t stream) {
  const float* feat  = (const float*)d_in[0];
  const float* w1    = (const float*)d_in[1];
  const float* b1    = (const float*)d_in[2];
  const float* w2    = (const float*)d_in[3];
  const float* b2    = (const float*)d_in[4];
  const float* w3    = (const float*)d_in[5];
  const float* b3    = (const float*)d_in[6];
  const float* gamma = (const float*)d_in[7];
  float* out = (float*)d_out;
  char* ws = (char*)d_ws;
  unsigned short* Q = (unsigned short*)(ws + OFF_Q);
  unsigned short* K = (unsigned short*)(ws + OFF_K);
  unsigned short* V = (unsigned short*)(ws + OFF_V);

  hipLaunchKernelGGL(k_proj, dim3(72, NB), dim3(256), 0, stream,
                     feat, w1, b1, w2, b2, w3, b3, Q, K, V);
  hipLaunchKernelGGL(k_attn, dim3(768), dim3(192), 0, stream,
                     Q, K, V, feat, gamma, out);
}

// Round 4
// 155.350 us; speedup vs baseline: 1.2522x; 1.0824x over previous
//
#include <hip/hip_runtime.h>
#include <stdint.h>

// Problem constants (B,C,H,W = 8,256,48,48)
#define NB  8
#define NC  256
#define NCR 32
#define NSP 2304  // N = H*W
#define LOG2E 1.44269504088896340736f

typedef __attribute__((ext_vector_type(8))) short short8;   // 8 x bf16 (4 VGPRs)
typedef __attribute__((ext_vector_type(4))) float f32x4;    // MFMA C/D frag
typedef __attribute__((ext_vector_type(4))) unsigned short us4;
typedef __attribute__((ext_vector_type(2))) unsigned int u32x2;

__device__ __forceinline__ unsigned short f2bf(float f) {
  union { float f; unsigned u; } a; a.f = f;
  unsigned r = (a.u + 0x7FFFu + ((a.u >> 16) & 1u)) >> 16;  // RNE
  return (unsigned short)r;
}

__device__ __forceinline__ float fexp2(float x) {
#if __has_builtin(__builtin_amdgcn_exp2f)
  return __builtin_amdgcn_exp2f(x);
#else
  return __exp2f(x);
#endif
}

// pack 4 fp32 -> 4 bf16 (RNE) as two dwords
__device__ __forceinline__ u32x2 pack4bf(float a, float b, float c, float d) {
  u32x2 r;
#if __has_builtin(__builtin_amdgcn_cvt_pk_bf16_f32)
  typedef __attribute__((ext_vector_type(2))) __bf16 bf2;
  union { bf2 v; unsigned u; } lo, hi;
  lo.v = __builtin_amdgcn_cvt_pk_bf16_f32(a, b);
  hi.v = __builtin_amdgcn_cvt_pk_bf16_f32(c, d);
  r[0] = lo.u; r[1] = hi.u;
#else
  r[0] = (unsigned)f2bf(a) | ((unsigned)f2bf(b) << 16);
  r[1] = (unsigned)f2bf(c) | ((unsigned)f2bf(d) << 16);
#endif
  return r;
}

typedef __attribute__((address_space(1))) const void* gvoidp;
typedef __attribute__((address_space(3))) void* lvoidp;
#define GLOADLDS16(g, l) __builtin_amdgcn_global_load_lds((gvoidp)(g), (lvoidp)(l), 16, 0, 0)

// ---------------------------------------------------------------------------
// Kernel 0: one-time weight prep. Concatenate w1(32x256) | w2(32x256) |
// w3(256x256) into bf16 WB[320][256] using the SAME RNE f2bf as before ->
// bit-identical downstream numerics. 80 blocks x 256 thr, 1 float4 each.
__global__ __launch_bounds__(256) void k_wprep(const float* __restrict__ w1,
    const float* __restrict__ w2, const float* __restrict__ w3,
    unsigned short* __restrict__ WB) {
  const int idx = blockIdx.x * 256 + threadIdx.x;   // 0..20479
  const int gid = idx * 4;                          // element index
  const int row = gid >> 8, col = gid & 255;
  const float* src;
  if (row < 32)       src = w1 + (size_t)row * NC + col;
  else if (row < 64)  src = w2 + (size_t)(row - 32) * NC + col;
  else                src = w3 + (size_t)(row - 64) * NC + col;
  float4 v = *(const float4*)src;
  us4 pk;
  pk[0] = f2bf(v.x); pk[1] = f2bf(v.y); pk[2] = f2bf(v.z); pk[3] = f2bf(v.w);
  *(us4*)(WB + (size_t)row * NC + col) = pk;
}

// ---------------------------------------------------------------------------
// Kernel 1 (fused transpose + QKV projection). Weights now pre-converted to
// bf16 WB[320][256] (rows = m0 ordering): per fragment ONE short8 load
// replaces 2x float4 + 8x f2bf. Q rows pre-scaled by log2(e) as before.
__global__ __launch_bounds__(256) void k_proj(const float* __restrict__ x,
    const unsigned short* __restrict__ WB, const float* __restrict__ b1,
    const float* __restrict__ b2, const float* __restrict__ b3,
    unsigned short* __restrict__ Q, unsigned short* __restrict__ K,
    unsigned short* __restrict__ V) {
  __shared__ unsigned short xs[32][264];  // [n][c], +8 pad
  const int n0 = blockIdx.x * 32, b = blockIdx.y;
  const int t = threadIdx.x, lane = t & 63, wave = t >> 6;
  const int col = lane & 15, quad = lane >> 4;
  const float* xb = x + (size_t)b * NC * NSP;
#pragma unroll
  for (int p = 0; p < 8; ++p) {
    const int crow = (t >> 3) + p * 32;     // 0..255
    const int n4 = (t & 7) * 4;             // 0..28
    float4 v = *(const float4*)(xb + (size_t)crow * NSP + n0 + n4);
    xs[n4 + 0][crow] = f2bf(v.x);
    xs[n4 + 1][crow] = f2bf(v.y);
    xs[n4 + 2][crow] = f2bf(v.z);
    xs[n4 + 3][crow] = f2bf(v.w);
  }
  __syncthreads();
  const f32x4 zero4 = {0.f, 0.f, 0.f, 0.f};
  f32x4 acc[5][2];
#pragma unroll
  for (int i = 0; i < 5; ++i)
#pragma unroll
    for (int j = 0; j < 2; ++j) acc[i][j] = zero4;

  for (int kc = 0; kc < 8; ++kc) {
    short8 bf[2];
#pragma unroll
    for (int nt = 0; nt < 2; ++nt)
      bf[nt] = *(const short8*)&xs[nt * 16 + col][kc * 32 + quad * 8];
#pragma unroll
    for (int ml = 0; ml < 5; ++ml) {
      const int m0 = (wave * 5 + ml) * 16;
      const short8 af = *(const short8*)(WB + (size_t)(m0 + col) * NC + kc * 32 + quad * 8);
#pragma unroll
      for (int nt = 0; nt < 2; ++nt)
        acc[ml][nt] = __builtin_amdgcn_mfma_f32_16x16x32_bf16(af, bf[nt], acc[ml][nt], 0, 0, 0);
    }
  }
#pragma unroll
  for (int ml = 0; ml < 5; ++ml) {
    const int m0 = (wave * 5 + ml) * 16;
    const float* bias;
    if (m0 < 32)      bias = b1 + m0;
    else if (m0 < 64) bias = b2 + (m0 - 32);
    else              bias = b3 + (m0 - 64);
    float bv[4];
#pragma unroll
    for (int r = 0; r < 4; ++r) bv[r] = bias[quad * 4 + r];
    if (m0 < 64) {  // Q or K : [b][n][32]
      unsigned short* dst = (m0 < 32) ? Q : K;
      const float scl = (m0 < 32) ? LOG2E : 1.0f;  // fold log2e into Q
      const int d0 = (m0 & 31) + quad * 4;
#pragma unroll
      for (int nt = 0; nt < 2; ++nt) {
        const int n = n0 + nt * 16 + col;
        us4 pk;
#pragma unroll
        for (int r = 0; r < 4; ++r) pk[r] = f2bf((acc[ml][nt][r] + bv[r]) * scl);
        *(us4*)(dst + ((size_t)b * NSP + n) * NCR + d0) = pk;
      }
    } else {        // V : [b][c][n]
      const int cbase = m0 - 64 + quad * 4;
#pragma unroll
      for (int nt = 0; nt < 2; ++nt) {
        const int n = n0 + nt * 16 + col;
#pragma unroll
        for (int r = 0; r < 4; ++r)
          V[((size_t)b * NC + cbase + r) * NSP + n] = f2bf(acc[ml][nt][r] + bv[r]);
      }
    }
  }
}

// ---------------------------------------------------------------------------
// Kernel 2 (fused attention) — R3 structure (R0 + batch-per-XCD swizzle +
// single-buffered wave-private Ps), plus s_setprio(1) around the PV MFMA
// cluster (T5: 3 independent blocks/CU give phase diversity).
__global__ __launch_bounds__(192) void k_attn(const unsigned short* __restrict__ Q,
    const unsigned short* __restrict__ K, const unsigned short* __restrict__ V,
    const float* __restrict__ feat, const float* __restrict__ gamma,
    float* __restrict__ out) {
  __shared__ __align__(16) unsigned short smem[19840];  // 39680 B
  unsigned short* Vs = smem;            // [buf][128 c][64 j] : 2 x 8192 u16
  unsigned short* Ps = smem + 16384;    // [wave][16 i][72] : 3 x 1152 u16
  // batch-per-XCD swizzle: lin&7 -> batch (one batch per XCD, L2-resident)
  const int lin = blockIdx.x;
  const int b = lin & 7;
  const int rest = lin >> 3;            // 0..95
  const int i0 = (rest % 48) * 48;
  const int ch = (rest / 48) * 128;
  const int t = threadIdx.x, lane = t & 63, wave = t >> 6;  // wave 0..2
  const int col = lane & 15, quad = lane >> 4;
  const int iw = i0 + wave * 16;
  const unsigned short* Qb = Q + (size_t)b * NSP * NCR;
  const unsigned short* Kb = K + (size_t)b * NSP * NCR;
  const unsigned short* Vb = V + (size_t)b * NC * NSP;
  unsigned short* PsW = Ps + wave * 1152;  // single buffer (wave-private)

  const short8 qa = *(const short8*)(Qb + (size_t)(iw + col) * NCR + quad * 8);
  const f32x4 zero4 = {0.f, 0.f, 0.f, 0.f};
  f32x4 acc[8];
#pragma unroll
  for (int ct = 0; ct < 8; ++ct) acc[ct] = zero4;
  float rs = 0.f;  // partial row-sum for i = col (this lane's quad's j-subset)
  // staging lane map: call q covers c-rows q*8..q*8+7 (8 rows x 8 chunks of 16B);
  // lane -> row r8 = lane>>3, phys chunk pc = lane&7 holding logical chunk pc^r8.
  const int r8 = lane >> 3, pc = lane & 7, jcs = pc ^ r8;

  // ---- prologue: kb(0), stage(0) -> buf0, scores(0) -> Ps
  short8 kb[4];
#pragma unroll
  for (int mt = 0; mt < 4; ++mt)
    kb[mt] = *(const short8*)(Kb + (size_t)(mt * 16 + col) * NCR + quad * 8);
#pragma unroll
  for (int cix = 0; cix < 6; ++cix) {
    const int q = wave * 6 + cix;          // 0..17; q>=16 skipped (wave-uniform)
    if (q < 16) {
      const unsigned short* g = Vb + (size_t)(ch + q * 8 + r8) * NSP + jcs * 8;
      GLOADLDS16(g, Vs + q * 512);
    }
  }
#pragma unroll
  for (int mt = 0; mt < 4; ++mt) {
    f32x4 s = __builtin_amdgcn_mfma_f32_16x16x32_bf16(kb[mt], qa, zero4, 0, 0, 0);
    const float e0 = fexp2(s[0]), e1 = fexp2(s[1]), e2 = fexp2(s[2]), e3 = fexp2(s[3]);
    rs += (e0 + e1) + (e2 + e3);
    *(u32x2*)(PsW + col * 72 + mt * 16 + quad * 4) = pack4bf(e0, e1, e2, e3);
  }

  // ---- main loop: one barrier per iteration
  for (int kc = 0; kc < 36; ++kc) {
    __syncthreads();  // Vs(kc) staged (vmcnt drained)
    const int bufc = kc & 1, bufn = bufc ^ 1;
    const int j1 = (kc + 1) * 64;
    const bool more = (kc + 1 < 36);
    if (more) {
      // kb(n+1) first (in-order vmcnt: retires before the staging loads)
#pragma unroll
      for (int mt = 0; mt < 4; ++mt)
        kb[mt] = *(const short8*)(Kb + (size_t)(j1 + mt * 16 + col) * NCR + quad * 8);
      // stage(n+1) -> Vs bufn (full PV+scores distance to drain before barrier)
#pragma unroll
      for (int cix = 0; cix < 6; ++cix) {
        const int q = wave * 6 + cix;
        if (q < 16) {
          const unsigned short* g = Vb + (size_t)(ch + q * 8 + r8) * NSP + j1 + jcs * 8;
          GLOADLDS16(g, Vs + bufn * 8192 + q * 512);
        }
      }
    }
    // PV(kc): reads Ps (this wave's, written last iter) + Vs bufc
    const unsigned short* vsc = Vs + bufc * 8192;
    __builtin_amdgcn_s_setprio(1);
#pragma unroll
    for (int kk = 0; kk < 2; ++kk) {
      const short8 pa = *(const short8*)(PsW + col * 72 + kk * 32 + quad * 8);
#pragma unroll
      for (int ct = 0; ct < 8; ++ct) {
        const short8 vbf = *(const short8*)(vsc + (ct * 16 + col) * 64 +
                                            (((kk * 4 + quad) ^ (col & 7)) * 8));
        acc[ct] = __builtin_amdgcn_mfma_f32_16x16x32_bf16(pa, vbf, acc[ct], 0, 0, 0);
      }
    }
    __builtin_amdgcn_s_setprio(0);
    if (more) {
      // scores(n+1) -> Ps (single buffer: overwrite AFTER this iter's PV reads;
      // wave-private + in-order DS makes this safe)
#pragma unroll
      for (int mt = 0; mt < 4; ++mt) {
        f32x4 s = __builtin_amdgcn_mfma_f32_16x16x32_bf16(kb[mt], qa, zero4, 0, 0, 0);
        const float e0 = fexp2(s[0]), e1 = fexp2(s[1]), e2 = fexp2(s[2]), e3 = fexp2(s[3]);
        rs += (e0 + e1) + (e2 + e3);
        *(u32x2*)(PsW + col * 72 + mt * 16 + quad * 4) = pack4bf(e0, e1, e2, e3);
      }
    }
  }

  // ---- l: sum the 4 quads of each col (full row-sum for i = col), then
  // redistribute to D-layout rows (i = quad*4 + r) for the epilogue.
  rs += __shfl_xor(rs, 16, 64);
  rs += __shfl_xor(rs, 32, 64);
  const float g = gamma[0];
  float rinv[4];
#pragma unroll
  for (int r = 0; r < 4; ++r) rinv[r] = g / __shfl(rs, quad * 4 + r, 64);

  // ---- epilogue: float4 over r (i-contiguous), 64B segments
  const float* fb = feat + (size_t)b * NC * NSP;
  float* ob = out + (size_t)b * NC * NSP;
#pragma unroll
  for (int ct = 0; ct < 8; ++ct) {
    const size_t a0 = (size_t)(ch + ct * 16 + col) * NSP + iw + quad * 4;
    float4 f = *(const float4*)(fb + a0);
    float4 o;
    o.x = acc[ct][0] * rinv[0] + f.x;
    o.y = acc[ct][1] * rinv[1] + f.y;
    o.z = acc[ct][2] * rinv[2] + f.z;
    o.w = acc[ct][3] * rinv[3] + f.w;
    *(float4*)(ob + a0) = o;
  }
}

// ---------------------------------------------------------------------------
// Workspace layout (bytes), total 11,960,320 (~11.4 MB):
//   Q  : [0, 1179648)            bf16 [8][2304][32]   (pre-scaled by log2e)
//   K  : [1179648, 2359296)      bf16 [8][2304][32]
//   V  : [2359296, 11796480)     bf16 [8][256][2304]
//   WB : [11796480, 11960320)    bf16 [320][256]      (w1|w2|w3 concat)
#define OFF_Q  0UL
#define OFF_K  1179648UL
#define OFF_V  2359296UL
#define OFF_WB 11796480UL

extern "C" void kernel_launch(void* const* d_in, const int* in_sizes, int n_in,
                              void* d_out, int out_size, void* d_ws, size_t ws_size,
                              hipStream_t stream) {
  const float* feat  = (const float*)d_in[0];
  const float* w1    = (const float*)d_in[1];
  const float* b1    = (const float*)d_in[2];
  const float* w2    = (const float*)d_in[3];
  const float* b2    = (const float*)d_in[4];
  const float* w3    = (const float*)d_in[5];
  const float* b3    = (const float*)d_in[6];
  const float* gamma = (const float*)d_in[7];
  float* out = (float*)d_out;
  char* ws = (char*)d_ws;
  unsigned short* Q  = (unsigned short*)(ws + OFF_Q);
  unsigned short* K  = (unsigned short*)(ws + OFF_K);
  unsigned short* V  = (unsigned short*)(ws + OFF_V);
  unsigned short* WB = (unsigned short*)(ws + OFF_WB);

  hipLaunchKernelGGL(k_wprep, dim3(80), dim3(256), 0, stream, w1, w2, w3, WB);
  hipLaunchKernelGGL(k_proj, dim3(72, NB), dim3(256), 0, stream,
                     feat, WB, b1, b2, b3, Q, K, V);
  hipLaunchKernelGGL(k_attn, dim3(768), dim3(192), 0, stream,
                     Q, K, V, feat, gamma, out);
}